// Round 8
// baseline (495.870 us; speedup 1.0000x reference)
//
#include <hip/hip_runtime.h>

#define NN 100000
#define NE 3200000
#define SCAN_CHUNK 1024

// bucket sort params
#define BSH 8
#define BKT_NODES 256                       // 1 << BSH
#define NBKT ((NN + BKT_NODES - 1) / BKT_NODES)   // 391
#define BIN_BLOCKS 256
#define EPB ((NE + BIN_BLOCKS - 1) / BIN_BLOCKS)  // 12500
#define GH (NBKT * BIN_BLOCKS)                    // 100096

typedef unsigned int uint;
typedef unsigned short ushort;
typedef __attribute__((ext_vector_type(8))) short short8;
typedef __attribute__((ext_vector_type(4))) float f32x4;

// async global->LDS, 16B per lane; dest = wave-uniform base + lane*16
__device__ inline void gload16(const void* g, void* l) {
    __builtin_amdgcn_global_load_lds(
        (const __attribute__((address_space(1))) void*)g,
        (__attribute__((address_space(3))) void*)l, 16, 0, 0);
}

// round fp32 -> bf16 (RNE), return upper 16 bits
__device__ inline ushort bf16rne(float x) {
    uint u = __float_as_uint(x);
    u += 0x7FFFu + ((u >> 16) & 1u);
    return (ushort)(u >> 16);
}
// split x into hi bf16 + lo bf16 (x ~= hi + lo)
__device__ inline void split2(float x, ushort& h, ushort& l) {
    h = bf16rne(x);
    float hf = __uint_as_float((uint)h << 16);
    l = bf16rne(x - hf);
}
// pack two fp32 -> two bf16 (RNE) in one uint (a = low, b = high)
__device__ inline uint bf16pair(float a, float b) {
    uint ua = __float_as_uint(a);
    uint ub = __float_as_uint(b);
    ua += 0x7FFFu + ((ua >> 16) & 1u);
    ub += 0x7FFFu + ((ub >> 16) & 1u);
    return (ua >> 16) | (ub & 0xFFFF0000u);
}
__device__ inline float bflo(uint u) { return __uint_as_float(u << 16); }
__device__ inline float bfhi(uint u) { return __uint_as_float(u & 0xFFFF0000u); }

// ---------------- bucket histogram ----------------
__global__ __launch_bounds__(256) void hist_bkt(const int* __restrict__ dst,
                                                int* __restrict__ ghist) {
    __shared__ int h[NBKT];
    int t = threadIdx.x;
    for (int i = t; i < NBKT; i += 256) h[i] = 0;
    __syncthreads();
    int beg = blockIdx.x * EPB;
    int end = beg + EPB; if (end > NE) end = NE;
    for (int e = beg + t; e < end; e += 256)
        atomicAdd(&h[dst[e] >> BSH], 1);
    __syncthreads();
    for (int i = t; i < NBKT; i += 256)
        ghist[i * BIN_BLOCKS + blockIdx.x] = h[i];
}

// ---------------- hierarchical scan: phase 1 ----------------
__global__ __launch_bounds__(256) void scan_p1(const int* __restrict__ cnt,
                                               int* __restrict__ bsum, int N) {
    int t = threadIdx.x;
    int base = blockIdx.x * SCAN_CHUNK + t * 4;
    int s = 0;
#pragma unroll
    for (int q = 0; q < 4; q++) {
        int i = base + q;
        if (i < N) s += cnt[i];
    }
    __shared__ int red[4];
#pragma unroll
    for (int off = 32; off; off >>= 1) s += __shfl_down(s, off, 64);
    if ((t & 63) == 0) red[t >> 6] = s;
    __syncthreads();
    if (t == 0) bsum[blockIdx.x] = red[0] + red[1] + red[2] + red[3];
}

// ---------------- phase 2 ----------------
__global__ void scan_p2(int* __restrict__ bsum, int nb) {
    __shared__ int s[128];
    int t = threadIdx.x;
    int v = (t < nb) ? bsum[t] : 0;
    s[t] = v;
    __syncthreads();
    for (int off = 1; off < 128; off <<= 1) {
        int x = s[t];
        int add = (t >= off) ? s[t - off] : 0;
        __syncthreads();
        s[t] = x + add;
        __syncthreads();
    }
    if (t < nb) bsum[t] = s[t] - v;  // exclusive
}

// ---------------- phase 3a: in-place exclusive scan ----------------
__global__ __launch_bounds__(256) void scan_p3_plain(int* __restrict__ data,
                                                     const int* __restrict__ bsum, int N) {
    __shared__ int ts[256];
    int t = threadIdx.x;
    int base = blockIdx.x * SCAN_CHUNK + t * 4;
    int c[4];
    int s = 0;
#pragma unroll
    for (int q = 0; q < 4; q++) {
        int i = base + q;
        c[q] = (i < N) ? data[i] : 0;
        s += c[q];
    }
    ts[t] = s;
    __syncthreads();
    for (int off = 1; off < 256; off <<= 1) {
        int x = ts[t];
        int add = (t >= off) ? ts[t - off] : 0;
        __syncthreads();
        ts[t] = x + add;
        __syncthreads();
    }
    int run = bsum[blockIdx.x] + ts[t] - s;
#pragma unroll
    for (int q = 0; q < 4; q++) {
        int i = base + q;
        if (i < N) { data[i] = run; run += c[q]; }
    }
}

// ---------------- phase 3b: scan + rowptr + dinv ----------------
__global__ __launch_bounds__(256) void scan_p3_deg(const int* __restrict__ cnt,
                                                   const int* __restrict__ bsum,
                                                   int* __restrict__ rowptr,
                                                   float* __restrict__ dinv, int N) {
    __shared__ int ts[256];
    int t = threadIdx.x;
    int base = blockIdx.x * SCAN_CHUNK + t * 4;
    int c[4];
    int s = 0;
#pragma unroll
    for (int q = 0; q < 4; q++) {
        int i = base + q;
        c[q] = (i < N) ? cnt[i] : 0;
        s += c[q];
    }
    ts[t] = s;
    __syncthreads();
    for (int off = 1; off < 256; off <<= 1) {
        int x = ts[t];
        int add = (t >= off) ? ts[t - off] : 0;
        __syncthreads();
        ts[t] = x + add;
        __syncthreads();
    }
    int run = bsum[blockIdx.x] + ts[t] - s;
#pragma unroll
    for (int q = 0; q < 4; q++) {
        int i = base + q;
        if (i < N) {
            rowptr[i] = run;
            dinv[i] = 1.0f / sqrtf((float)(c[q] + 1));  // +1 self-loop
            run += c[q];
        }
    }
    if (base < N && N <= base + 4) rowptr[N] = run;
}

// ---------------- bin edges into bucket-segmented records ----------------
__global__ __launch_bounds__(256) void bin_edges(const int* __restrict__ src,
                                                 const int* __restrict__ dst,
                                                 const int* __restrict__ ghist,
                                                 uint* __restrict__ binned) {
    __shared__ int cur[NBKT];
    int t = threadIdx.x;
    for (int i = t; i < NBKT; i += 256) cur[i] = ghist[i * BIN_BLOCKS + blockIdx.x];
    __syncthreads();
    int beg = blockIdx.x * EPB;
    int end = beg + EPB; if (end > NE) end = NE;
    for (int e = beg + t; e < end; e += 256) {
        int d = dst[e];
        int b = d >> BSH;
        int p = atomicAdd(&cur[b], 1);
        binned[p] = ((uint)src[e] << BSH) | (uint)(d & (BKT_NODES - 1));
    }
}

// ---------------- per-bucket node degree count ----------------
__global__ __launch_bounds__(256) void bucket_count(const uint* __restrict__ binned,
                                                    const int* __restrict__ ghist,
                                                    int* __restrict__ cnt) {
    __shared__ int c[BKT_NODES];
    int t = threadIdx.x;
    int bkt = blockIdx.x;
    for (int i = t; i < BKT_NODES; i += 256) c[i] = 0;
    __syncthreads();
    int beg = ghist[bkt * BIN_BLOCKS];
    int end = (bkt == NBKT - 1) ? NE : ghist[(bkt + 1) * BIN_BLOCKS];
    for (int j = beg + t; j < end; j += 256)
        atomicAdd(&c[binned[j] & (BKT_NODES - 1)], 1);
    __syncthreads();
    int base = bkt * BKT_NODES;
    int nb = NN - base; if (nb > BKT_NODES) nb = BKT_NODES;
    for (int i = t; i < nb; i += 256) cnt[base + i] = c[i];
}

// ---------------- per-bucket CSR fill ----------------
__global__ __launch_bounds__(256) void csr_fill(const uint* __restrict__ binned,
                                                const int* __restrict__ ghist,
                                                const int* __restrict__ rowptr,
                                                int* __restrict__ col) {
    __shared__ int fill[BKT_NODES];
    int t = threadIdx.x;
    int bkt = blockIdx.x;
    for (int i = t; i < BKT_NODES; i += 256) fill[i] = 0;
    __syncthreads();
    int beg = ghist[bkt * BIN_BLOCKS];
    int end = (bkt == NBKT - 1) ? NE : ghist[(bkt + 1) * BIN_BLOCKS];
    int base = bkt * BKT_NODES;
    for (int j = beg + t; j < end; j += 256) {
        uint r = binned[j];
        int dl = r & (BKT_NODES - 1);
        int p = rowptr[base + dl] + atomicAdd(&fill[dl], 1);
        col[p] = (int)(r >> BSH);
    }
}

// ---------------- W transpose + bf16 hi/lo split: W[K][128] -> Wt[128][K] ----------------
template <int K>
__global__ __launch_bounds__(256) void wsplit(const float* __restrict__ W,
                                              ushort* __restrict__ Wth,
                                              ushort* __restrict__ Wtl) {
    __shared__ float tile[32][128];
    int t = threadIdx.x;
    int kb = blockIdx.x;
    {
        int k = t >> 3, cq = t & 7;
#pragma unroll
        for (int q = 0; q < 4; q++) {
            float4 v = *(const float4*)&W[(size_t)(kb * 32 + k) * 128 + cq * 16 + q * 4];
            *(float4*)&tile[k][cq * 16 + q * 4] = v;
        }
    }
    __syncthreads();
    {
        int c = t >> 1, g = t & 1;
        ushort hs[16], ls[16];
#pragma unroll
        for (int i = 0; i < 16; i++) split2(tile[g * 16 + i][c], hs[i], ls[i]);
        uint h[8], lo[8];
#pragma unroll
        for (int i = 0; i < 8; i++) {
            h[i] = (uint)hs[2 * i] | ((uint)hs[2 * i + 1] << 16);
            lo[i] = (uint)ls[2 * i] | ((uint)ls[2 * i + 1] << 16);
        }
        size_t o = (size_t)c * K + kb * 32 + g * 16;
        *(uint4*)&Wth[o] = make_uint4(h[0], h[1], h[2], h[3]);
        *(uint4*)&Wth[o + 8] = make_uint4(h[4], h[5], h[6], h[7]);
        *(uint4*)&Wtl[o] = make_uint4(lo[0], lo[1], lo[2], lo[3]);
        *(uint4*)&Wtl[o + 8] = make_uint4(lo[4], lo[5], lo[6], lo[7]);
    }
}

// ---------------- MFMA GEMM v2: 128x128 tile, gload_lds B, reg-prefetch A ----------------
// X[M][K] fp32 @ Wt[128][K] (bf16 hi/lo planes) -> Y packed bf16, pre-scaled by dinv[row].
// LDS planes in [idx][kg] 16B-chunk order: A chunk (row*4+kg), B chunk (col*4+kg) -> linear,
// conflict-free for both global_load_lds (linear dest) and MFMA fragment ds_read_b128.
template <int K>
__global__ __launch_bounds__(256) void mfma_gemm(const float* __restrict__ X,
                                                 const ushort* __restrict__ Wth,
                                                 const ushort* __restrict__ Wtl,
                                                 const float* __restrict__ dinv,
                                                 uint* __restrict__ Y, int M) {
    __shared__ char smem[32 * 1024];
    char* aHi = smem;             // 8 KB: 128 rows x 4 kg-chunks
    char* aLo = smem + 8192;      // 8 KB
    char* bHi = smem + 16384;     // 8 KB: 128 cols x 4 kg-chunks
    char* bLo = smem + 24576;     // 8 KB
    int tid = threadIdx.x;
    int w = tid >> 6, l = tid & 63;
    int rowBase = blockIdx.x * 128;

    f32x4 acc[2][8];
#pragma unroll
    for (int mf = 0; mf < 2; mf++)
#pragma unroll
        for (int n = 0; n < 8; n++) acc[mf][n] = (f32x4){0.f, 0.f, 0.f, 0.f};

    // A staging: thread t -> row t>>1 (0..127), k-half t&1 (16 fp32 = 64B)
    int sRow = tid >> 1, sKp = tid & 1;
    int gRow = rowBase + sRow;
    bool rowOK = gRow < M;
    size_t aBase = (size_t)(rowOK ? gRow : 0) * K + sKp * 16;

    float4 a0, a1, a2, a3;
    a0 = a1 = a2 = a3 = make_float4(0.f, 0.f, 0.f, 0.f);
    if (rowOK) {
        a0 = *(const float4*)&X[aBase];
        a1 = *(const float4*)&X[aBase + 4];
        a2 = *(const float4*)&X[aBase + 8];
        a3 = *(const float4*)&X[aBase + 12];
    }

    int fc = l & 15, fkg = l >> 4;  // fragment col/row-in-tile and k-group

    for (int kt = 0; kt < K; kt += 32) {
        // ---- issue B async global->LDS first (L2 latency hides under A split) ----
#pragma unroll
        for (int i = 0; i < 2; i++) {
            int cb = (i * 4 + w) * 64;          // wave-uniform chunk base
            int c = cb + l;
            int colb = c >> 2, kg = c & 3;
            size_t go = (size_t)colb * K + kt + kg * 8;
            gload16(&Wth[go], bHi + cb * 16);
            gload16(&Wtl[go], bLo + cb * 16);
        }
        // ---- split A regs -> LDS planes ----
        {
            float v[16] = {a0.x, a0.y, a0.z, a0.w, a1.x, a1.y, a1.z, a1.w,
                           a2.x, a2.y, a2.z, a2.w, a3.x, a3.y, a3.z, a3.w};
            uint hh[8], hl[8];
#pragma unroll
            for (int i = 0; i < 8; i++) {
                ushort h0, l0, h1, l1;
                split2(v[2 * i], h0, l0);
                split2(v[2 * i + 1], h1, l1);
                hh[i] = (uint)h0 | ((uint)h1 << 16);
                hl[i] = (uint)l0 | ((uint)l1 << 16);
            }
            int wa = (sRow * 4 + sKp * 2) * 16;  // byte offset of first chunk
            *(uint4*)(aHi + wa) = make_uint4(hh[0], hh[1], hh[2], hh[3]);
            *(uint4*)(aHi + wa + 16) = make_uint4(hh[4], hh[5], hh[6], hh[7]);
            *(uint4*)(aLo + wa) = make_uint4(hl[0], hl[1], hl[2], hl[3]);
            *(uint4*)(aLo + wa + 16) = make_uint4(hl[4], hl[5], hl[6], hl[7]);
        }
        __syncthreads();  // drains gload_lds (vmcnt) + ds_writes (lgkmcnt)

        // ---- prefetch next A tile into regs (HBM latency hides under MFMA) ----
        if (kt + 32 < K && rowOK) {
            size_t nb = aBase + kt + 32;
            a0 = *(const float4*)&X[nb];
            a1 = *(const float4*)&X[nb + 4];
            a2 = *(const float4*)&X[nb + 8];
            a3 = *(const float4*)&X[nb + 12];
        }

        // ---- MFMA: 2 m-frags x 8 n-frags x 3 terms ----
#pragma unroll
        for (int mf = 0; mf < 2; mf++) {
            int aoff = (((2 * w + mf) * 16 + fc) * 4 + fkg) * 16;
            short8 ah = *(const short8*)(aHi + aoff);
            short8 al = *(const short8*)(aLo + aoff);
#pragma unroll
            for (int n = 0; n < 8; n++) {
                int boff = ((16 * n + fc) * 4 + fkg) * 16;
                short8 bh = *(const short8*)(bHi + boff);
                short8 bl = *(const short8*)(bLo + boff);
                acc[mf][n] = __builtin_amdgcn_mfma_f32_16x16x32_bf16(ah, bh, acc[mf][n], 0, 0, 0);
                acc[mf][n] = __builtin_amdgcn_mfma_f32_16x16x32_bf16(ah, bl, acc[mf][n], 0, 0, 0);
                acc[mf][n] = __builtin_amdgcn_mfma_f32_16x16x32_bf16(al, bh, acc[mf][n], 0, 0, 0);
            }
        }
        __syncthreads();
    }

    // ---- epilogue: D[row=(l>>4)*4+r][col=16n+fc] * dinv -> packed bf16 pairs ----
#pragma unroll
    for (int mf = 0; mf < 2; mf++) {
        float dscale[4];
#pragma unroll
        for (int r = 0; r < 4; r++) {
            int row = rowBase + (2 * w + mf) * 16 + fkg * 4 + r;
            dscale[r] = (row < M) ? dinv[row] : 0.f;
        }
#pragma unroll
        for (int n = 0; n < 8; n++) {
#pragma unroll
            for (int r = 0; r < 4; r++) {
                float val = acc[mf][n][r] * dscale[r];
                float p = __shfl_xor(val, 1, 64);
                int row = rowBase + (2 * w + mf) * 16 + fkg * 4 + r;
                if (!(l & 1) && row < M)
                    Y[(size_t)row * 64 + 8 * n + (fc >> 1)] = bf16pair(val, p);
            }
        }
    }
}

// ---------------- small GEMM, N=5, K=128 (fp32 in/out) ----------------
__global__ void gemm_n5(const float* __restrict__ X, const float* __restrict__ W,
                        float* __restrict__ Y, int M) {
    int idx = blockIdx.x * 256 + threadIdx.x;
    int row = idx / 5, c = idx % 5;
    if (row >= M) return;
    float acc = 0.f;
#pragma unroll 8
    for (int k = 0; k < 128; k++) acc += X[row * 128 + k] * W[k * 5 + c];
    Y[row * 5 + c] = acc;
}

// ---------------- pack h5: fp32[5] * dinv[row] -> 8 bf16 (16B, padded) ----------------
__global__ void pack5(const float* __restrict__ Y, const float* __restrict__ dinv,
                      uint4* __restrict__ hc, int N) {
    int node = blockIdx.x * 256 + threadIdx.x;
    if (node >= N) return;
    float di = dinv[node];
    float v0 = Y[node * 5 + 0] * di;
    float v1 = Y[node * 5 + 1] * di;
    float v2 = Y[node * 5 + 2] * di;
    float v3 = Y[node * 5 + 3] * di;
    float v4 = Y[node * 5 + 4] * di;
    hc[node] = make_uint4(bf16pair(v0, v1), bf16pair(v2, v3), bf16pair(v4, 0.f), 0u);
}

#define ACC8(v)                         \
    a0 += bflo(v.x); a1 += bfhi(v.x);   \
    a2 += bflo(v.y); a3 += bfhi(v.y);   \
    a4 += bflo(v.z); a5 += bfhi(v.z);   \
    a6 += bflo(v.w); a7 += bfhi(v.w);

// ---------------- CSR aggregation, dim 128: wave/node, deep-unrolled gathers ----------------
__global__ __launch_bounds__(256) void agg128_v3(const uint4* __restrict__ hb4,
                                                 const int* __restrict__ rowptr,
                                                 const int* __restrict__ col,
                                                 const float* __restrict__ dinv,
                                                 const float* __restrict__ bias,
                                                 float* __restrict__ out, int N, int do_relu) {
    int wave = threadIdx.x >> 6;
    int lane = threadIdx.x & 63;
    int node = blockIdx.x * 4 + wave;
    if (node >= N) return;
    int g = lane >> 4;    // edge slot 0..3
    int q = lane & 15;    // dim-octet: dims [q*8, q*8+8)
    int beg = rowptr[node], end = rowptr[node + 1];
    float a0 = 0.f, a1 = 0.f, a2 = 0.f, a3 = 0.f, a4 = 0.f, a5 = 0.f, a6 = 0.f, a7 = 0.f;

    int j = beg;
    // 16-edge unrolled main loop: 4 independent gathers in flight per wave
    for (; j + 16 <= end; j += 16) {
        int s0 = col[j + g];
        int s1 = col[j + 4 + g];
        int s2 = col[j + 8 + g];
        int s3 = col[j + 12 + g];
        uint4 v0 = hb4[(size_t)s0 * 16 + q];
        uint4 v1 = hb4[(size_t)s1 * 16 + q];
        uint4 v2 = hb4[(size_t)s2 * 16 + q];
        uint4 v3 = hb4[(size_t)s3 * 16 + q];
        ACC8(v0); ACC8(v1); ACC8(v2); ACC8(v3);
    }
    // 8-edge step
    if (j + 8 <= end) {
        int s0 = col[j + g];
        int s1 = col[j + 4 + g];
        uint4 v0 = hb4[(size_t)s0 * 16 + q];
        uint4 v1 = hb4[(size_t)s1 * 16 + q];
        ACC8(v0); ACC8(v1);
        j += 8;
    }
    // masked tail (<8 edges)
    if (j < end) {
        int jj0 = j + g, jj1 = j + 4 + g;
        bool p0 = jj0 < end, p1 = jj1 < end;
        int s0 = p0 ? col[jj0] : node;
        int s1 = p1 ? col[jj1] : node;
        uint4 v0 = hb4[(size_t)s0 * 16 + q];
        uint4 v1 = hb4[(size_t)s1 * 16 + q];
        if (!p0) v0 = make_uint4(0u, 0u, 0u, 0u);
        if (!p1) v1 = make_uint4(0u, 0u, 0u, 0u);
        ACC8(v0); ACC8(v1);
    }
    // reduce across the 4 edge-slot groups
#pragma unroll
    for (int off = 16; off <= 32; off <<= 1) {
        a0 += __shfl_xor(a0, off, 64);
        a1 += __shfl_xor(a1, off, 64);
        a2 += __shfl_xor(a2, off, 64);
        a3 += __shfl_xor(a3, off, 64);
        a4 += __shfl_xor(a4, off, 64);
        a5 += __shfl_xor(a5, off, 64);
        a6 += __shfl_xor(a6, off, 64);
        a7 += __shfl_xor(a7, off, 64);
    }
    if (g == 0) {
        // self term: hb4[node] is already dinv[node]*h[node]
        uint4 vs = hb4[(size_t)node * 16 + q];
        ACC8(vs);
        float di = dinv[node];
        const float4* bias4 = (const float4*)bias;
        float4 bb0 = bias4[q * 2], bb1 = bias4[q * 2 + 1];
        float o0 = a0 * di + bb0.x, o1 = a1 * di + bb0.y;
        float o2 = a2 * di + bb0.z, o3 = a3 * di + bb0.w;
        float o4 = a4 * di + bb1.x, o5 = a5 * di + bb1.y;
        float o6 = a6 * di + bb1.z, o7 = a7 * di + bb1.w;
        if (do_relu) {
            o0 = fmaxf(o0, 0.f); o1 = fmaxf(o1, 0.f);
            o2 = fmaxf(o2, 0.f); o3 = fmaxf(o3, 0.f);
            o4 = fmaxf(o4, 0.f); o5 = fmaxf(o5, 0.f);
            o6 = fmaxf(o6, 0.f); o7 = fmaxf(o7, 0.f);
        }
        float4* out4 = (float4*)out;
        out4[(size_t)node * 32 + q * 2] = make_float4(o0, o1, o2, o3);
        out4[(size_t)node * 32 + q * 2 + 1] = make_float4(o4, o5, o6, o7);
    }
}

// ---------------- CSR aggregation, dim 5 (packed bf16 rows): thread per node ----------------
__global__ void agg5_v2(const uint4* __restrict__ hc, const int* __restrict__ rowptr,
                        const int* __restrict__ col, const float* __restrict__ dinv,
                        const float* __restrict__ b3, float* __restrict__ out, int N) {
    int node = blockIdx.x * 256 + threadIdx.x;
    if (node >= N) return;
    float a0 = 0.f, a1 = 0.f, a2 = 0.f, a3 = 0.f, a4 = 0.f;
    int beg = rowptr[node], end = rowptr[node + 1];
#pragma unroll 2
    for (int j = beg; j < end; ++j) {
        uint4 v = hc[col[j]];
        a0 += bflo(v.x); a1 += bfhi(v.x);
        a2 += bflo(v.y); a3 += bfhi(v.y);
        a4 += bflo(v.z);
    }
    // self term (hc[node] pre-scaled by dinv)
    uint4 vs = hc[node];
    a0 += bflo(vs.x); a1 += bfhi(vs.x);
    a2 += bflo(vs.y); a3 += bfhi(vs.y);
    a4 += bflo(vs.z);
    float di = dinv[node];
    out[node * 5 + 0] = a0 * di + b3[0];
    out[node * 5 + 1] = a1 * di + b3[1];
    out[node * 5 + 2] = a2 * di + b3[2];
    out[node * 5 + 3] = a3 * di + b3[3];
    out[node * 5 + 4] = a4 * di + b3[4];
}

static inline size_t align512(size_t x) { return (x + 511) & ~(size_t)511; }

extern "C" void kernel_launch(void* const* d_in, const int* in_sizes, int n_in,
                              void* d_out, int out_size, void* d_ws, size_t ws_size,
                              hipStream_t stream) {
    const float* x  = (const float*)d_in[0];
    const int* ei   = (const int*)d_in[1];
    const float* W1 = (const float*)d_in[2];
    const float* b1 = (const float*)d_in[3];
    const float* W2 = (const float*)d_in[4];
    const float* b2 = (const float*)d_in[5];
    const float* W3 = (const float*)d_in[6];
    const float* b3 = (const float*)d_in[7];
    const int* src = ei;
    const int* dst = ei + NE;

    char* ws = (char*)d_ws;
    size_t off = 0;
    int* cnt = (int*)(ws + off);        off += align512((size_t)NN * 4);
    int* rowptr = (int*)(ws + off);     off += align512((size_t)(NN + 1) * 4);
    float* dinv = (float*)(ws + off);   off += align512((size_t)NN * 4);
    int* bsum = (int*)(ws + off);       off += align512((size_t)128 * 4);
    int* ghist = (int*)(ws + off);      off += align512((size_t)GH * 4);
    ushort* wt1h = (ushort*)(ws + off); off += align512((size_t)128 * 384 * 2);
    ushort* wt1l = (ushort*)(ws + off); off += align512((size_t)128 * 384 * 2);
    ushort* wt2h = (ushort*)(ws + off); off += align512((size_t)128 * 128 * 2);
    ushort* wt2l = (ushort*)(ws + off); off += align512((size_t)128 * 128 * 2);
    int* col = (int*)(ws + off);        off += align512((size_t)NE * 4);
    uint* hb = (uint*)(ws + off);       off += align512((size_t)NN * 64 * 4);   // bf16 dinv*h (packed)
    float* bufF = (float*)(ws + off);   off += align512((size_t)NN * 128 * 4);  // fp32 agg out
    float* bufC = (float*)(ws + off);   off += align512((size_t)NN * 5 * 4);
    uint4* hc = (uint4*)(ws + off);     off += align512((size_t)NN * 16);       // packed bf16 dinv*h5
    uint* binned = (uint*)bufF;  // alias: binned dead before bufF's first write
    (void)ws_size;

    // ---- W transpose + hi/lo split ----
    wsplit<384><<<12, 256, 0, stream>>>(W1, wt1h, wt1l);
    wsplit<128><<<4, 256, 0, stream>>>(W2, wt2h, wt2l);

    // ---- build CSR (by dst) + dinv, bucket-sorted for write locality ----
    hist_bkt<<<BIN_BLOCKS, 256, 0, stream>>>(dst, ghist);
    {
        int nb = (GH + SCAN_CHUNK - 1) / SCAN_CHUNK;  // 98
        scan_p1<<<nb, 256, 0, stream>>>(ghist, bsum, GH);
        scan_p2<<<1, 128, 0, stream>>>(bsum, nb);
        scan_p3_plain<<<nb, 256, 0, stream>>>(ghist, bsum, GH);
    }
    bin_edges<<<BIN_BLOCKS, 256, 0, stream>>>(src, dst, ghist, binned);
    bucket_count<<<NBKT, 256, 0, stream>>>(binned, ghist, cnt);
    {
        int nb = (NN + SCAN_CHUNK - 1) / SCAN_CHUNK;  // 98
        scan_p1<<<nb, 256, 0, stream>>>(cnt, bsum, NN);
        scan_p2<<<1, 128, 0, stream>>>(bsum, nb);
        scan_p3_deg<<<nb, 256, 0, stream>>>(cnt, bsum, rowptr, dinv, NN);
    }
    csr_fill<<<NBKT, 256, 0, stream>>>(binned, ghist, rowptr, col);

    int gemm_blocks = (NN + 127) / 128;  // 782
    // ---- layer 1 ----
    mfma_gemm<384><<<gemm_blocks, 256, 0, stream>>>(x, wt1h, wt1l, dinv, hb, NN);
    agg128_v3<<<(NN + 3) / 4, 256, 0, stream>>>((const uint4*)hb, rowptr, col, dinv, b1, bufF, NN, 1);
    // ---- layer 2 ----
    mfma_gemm<128><<<gemm_blocks, 256, 0, stream>>>(bufF, wt2h, wt2l, dinv, hb, NN);
    agg128_v3<<<(NN + 3) / 4, 256, 0, stream>>>((const uint4*)hb, rowptr, col, dinv, b2, bufF, NN, 1);
    // ---- layer 3 ----
    gemm_n5<<<((NN * 5) + 255) / 256, 256, 0, stream>>>(bufF, W3, bufC, NN);
    pack5<<<(NN + 255) / 256, 256, 0, stream>>>(bufC, dinv, hc, NN);
    agg5_v2<<<(NN + 255) / 256, 256, 0, stream>>>(hc, rowptr, col, dinv, b3, (float*)d_out, NN);
}

// Round 9
// 427.782 us; speedup vs baseline: 1.1592x; 1.1592x over previous
//
#include <hip/hip_runtime.h>
#include <hip/hip_fp16.h>

#define NN 100000
#define NE 3200000
#define SCAN_CHUNK 1024

// bucket sort params
#define BSH 8
#define BKT_NODES 256                       // 1 << BSH
#define NBKT ((NN + BKT_NODES - 1) / BKT_NODES)   // 391
#define BIN_BLOCKS 256
#define EPB ((NE + BIN_BLOCKS - 1) / BIN_BLOCKS)  // 12500
#define GH (NBKT * BIN_BLOCKS)                    // 100096

typedef unsigned int uint;
typedef unsigned short ushort;
typedef __attribute__((ext_vector_type(8))) _Float16 half8;
typedef __attribute__((ext_vector_type(4))) float f32x4;

// async global->LDS, 16B per lane; dest = wave-uniform base + lane*16
__device__ inline void gload16(const void* g, void* l) {
    __builtin_amdgcn_global_load_lds(
        (const __attribute__((address_space(1))) void*)g,
        (__attribute__((address_space(3))) void*)l, 16, 0, 0);
}

// fp16 helpers (RNE via v_cvt_f16_f32)
__device__ inline uint f2h_pair(float a, float b) {
    return (uint)__half_as_ushort(__float2half(a)) |
           ((uint)__half_as_ushort(__float2half(b)) << 16);
}
__device__ inline float h2f_lo(uint u) { return __half2float(__ushort_as_half((ushort)(u & 0xFFFFu))); }
__device__ inline float h2f_hi(uint u) { return __half2float(__ushort_as_half((ushort)(u >> 16))); }
// split fp32 -> fp16 hi + lo (x ~= hi + lo)
__device__ inline void splitH(float x, ushort& h, ushort& l) {
    __half hh = __float2half(x);
    h = __half_as_ushort(hh);
    l = __half_as_ushort(__float2half(x - __half2float(hh)));
}

// ---------------- bucket histogram ----------------
__global__ __launch_bounds__(256) void hist_bkt(const int* __restrict__ dst,
                                                int* __restrict__ ghist) {
    __shared__ int h[NBKT];
    int t = threadIdx.x;
    for (int i = t; i < NBKT; i += 256) h[i] = 0;
    __syncthreads();
    int beg = blockIdx.x * EPB;
    int end = beg + EPB; if (end > NE) end = NE;
    for (int e = beg + t; e < end; e += 256)
        atomicAdd(&h[dst[e] >> BSH], 1);
    __syncthreads();
    for (int i = t; i < NBKT; i += 256)
        ghist[i * BIN_BLOCKS + blockIdx.x] = h[i];
}

// ---------------- hierarchical scan: phase 1 ----------------
__global__ __launch_bounds__(256) void scan_p1(const int* __restrict__ cnt,
                                               int* __restrict__ bsum, int N) {
    int t = threadIdx.x;
    int base = blockIdx.x * SCAN_CHUNK + t * 4;
    int s = 0;
#pragma unroll
    for (int q = 0; q < 4; q++) {
        int i = base + q;
        if (i < N) s += cnt[i];
    }
    __shared__ int red[4];
#pragma unroll
    for (int off = 32; off; off >>= 1) s += __shfl_down(s, off, 64);
    if ((t & 63) == 0) red[t >> 6] = s;
    __syncthreads();
    if (t == 0) bsum[blockIdx.x] = red[0] + red[1] + red[2] + red[3];
}

// ---------------- phase 2 ----------------
__global__ void scan_p2(int* __restrict__ bsum, int nb) {
    __shared__ int s[128];
    int t = threadIdx.x;
    int v = (t < nb) ? bsum[t] : 0;
    s[t] = v;
    __syncthreads();
    for (int off = 1; off < 128; off <<= 1) {
        int x = s[t];
        int add = (t >= off) ? s[t - off] : 0;
        __syncthreads();
        s[t] = x + add;
        __syncthreads();
    }
    if (t < nb) bsum[t] = s[t] - v;  // exclusive
}

// ---------------- phase 3a: in-place exclusive scan ----------------
__global__ __launch_bounds__(256) void scan_p3_plain(int* __restrict__ data,
                                                     const int* __restrict__ bsum, int N) {
    __shared__ int ts[256];
    int t = threadIdx.x;
    int base = blockIdx.x * SCAN_CHUNK + t * 4;
    int c[4];
    int s = 0;
#pragma unroll
    for (int q = 0; q < 4; q++) {
        int i = base + q;
        c[q] = (i < N) ? data[i] : 0;
        s += c[q];
    }
    ts[t] = s;
    __syncthreads();
    for (int off = 1; off < 256; off <<= 1) {
        int x = ts[t];
        int add = (t >= off) ? ts[t - off] : 0;
        __syncthreads();
        ts[t] = x + add;
        __syncthreads();
    }
    int run = bsum[blockIdx.x] + ts[t] - s;
#pragma unroll
    for (int q = 0; q < 4; q++) {
        int i = base + q;
        if (i < N) { data[i] = run; run += c[q]; }
    }
}

// ---------------- phase 3b: scan + rowptr + dinv ----------------
__global__ __launch_bounds__(256) void scan_p3_deg(const int* __restrict__ cnt,
                                                   const int* __restrict__ bsum,
                                                   int* __restrict__ rowptr,
                                                   float* __restrict__ dinv, int N) {
    __shared__ int ts[256];
    int t = threadIdx.x;
    int base = blockIdx.x * SCAN_CHUNK + t * 4;
    int c[4];
    int s = 0;
#pragma unroll
    for (int q = 0; q < 4; q++) {
        int i = base + q;
        c[q] = (i < N) ? cnt[i] : 0;
        s += c[q];
    }
    ts[t] = s;
    __syncthreads();
    for (int off = 1; off < 256; off <<= 1) {
        int x = ts[t];
        int add = (t >= off) ? ts[t - off] : 0;
        __syncthreads();
        ts[t] = x + add;
        __syncthreads();
    }
    int run = bsum[blockIdx.x] + ts[t] - s;
#pragma unroll
    for (int q = 0; q < 4; q++) {
        int i = base + q;
        if (i < N) {
            rowptr[i] = run;
            dinv[i] = 1.0f / sqrtf((float)(c[q] + 1));  // +1 self-loop
            run += c[q];
        }
    }
    if (base < N && N <= base + 4) rowptr[N] = run;
}

// ---------------- bin edges into bucket-segmented records ----------------
__global__ __launch_bounds__(256) void bin_edges(const int* __restrict__ src,
                                                 const int* __restrict__ dst,
                                                 const int* __restrict__ ghist,
                                                 uint* __restrict__ binned) {
    __shared__ int cur[NBKT];
    int t = threadIdx.x;
    for (int i = t; i < NBKT; i += 256) cur[i] = ghist[i * BIN_BLOCKS + blockIdx.x];
    __syncthreads();
    int beg = blockIdx.x * EPB;
    int end = beg + EPB; if (end > NE) end = NE;
    for (int e = beg + t; e < end; e += 256) {
        int d = dst[e];
        int b = d >> BSH;
        int p = atomicAdd(&cur[b], 1);
        binned[p] = ((uint)src[e] << BSH) | (uint)(d & (BKT_NODES - 1));
    }
}

// ---------------- per-bucket node degree count ----------------
__global__ __launch_bounds__(256) void bucket_count(const uint* __restrict__ binned,
                                                    const int* __restrict__ ghist,
                                                    int* __restrict__ cnt) {
    __shared__ int c[BKT_NODES];
    int t = threadIdx.x;
    int bkt = blockIdx.x;
    for (int i = t; i < BKT_NODES; i += 256) c[i] = 0;
    __syncthreads();
    int beg = ghist[bkt * BIN_BLOCKS];
    int end = (bkt == NBKT - 1) ? NE : ghist[(bkt + 1) * BIN_BLOCKS];
    for (int j = beg + t; j < end; j += 256)
        atomicAdd(&c[binned[j] & (BKT_NODES - 1)], 1);
    __syncthreads();
    int base = bkt * BKT_NODES;
    int nb = NN - base; if (nb > BKT_NODES) nb = BKT_NODES;
    for (int i = t; i < nb; i += 256) cnt[base + i] = c[i];
}

// ---------------- per-bucket CSR fill ----------------
__global__ __launch_bounds__(256) void csr_fill(const uint* __restrict__ binned,
                                                const int* __restrict__ ghist,
                                                const int* __restrict__ rowptr,
                                                int* __restrict__ col) {
    __shared__ int fill[BKT_NODES];
    int t = threadIdx.x;
    int bkt = blockIdx.x;
    for (int i = t; i < BKT_NODES; i += 256) fill[i] = 0;
    __syncthreads();
    int beg = ghist[bkt * BIN_BLOCKS];
    int end = (bkt == NBKT - 1) ? NE : ghist[(bkt + 1) * BIN_BLOCKS];
    int base = bkt * BKT_NODES;
    for (int j = beg + t; j < end; j += 256) {
        uint r = binned[j];
        int dl = r & (BKT_NODES - 1);
        int p = rowptr[base + dl] + atomicAdd(&fill[dl], 1);
        col[p] = (int)(r >> BSH);
    }
}

// ---------------- W transpose + fp16 hi/lo split: W[K][128] -> Wt[128][K] ----------------
template <int K>
__global__ __launch_bounds__(256) void wsplit(const float* __restrict__ W,
                                              ushort* __restrict__ Wth,
                                              ushort* __restrict__ Wtl) {
    __shared__ float tile[32][128];
    int t = threadIdx.x;
    int kb = blockIdx.x;
    {
        int k = t >> 3, cq = t & 7;
#pragma unroll
        for (int q = 0; q < 4; q++) {
            float4 v = *(const float4*)&W[(size_t)(kb * 32 + k) * 128 + cq * 16 + q * 4];
            *(float4*)&tile[k][cq * 16 + q * 4] = v;
        }
    }
    __syncthreads();
    {
        int c = t >> 1, g = t & 1;
        ushort hs[16], ls[16];
#pragma unroll
        for (int i = 0; i < 16; i++) splitH(tile[g * 16 + i][c], hs[i], ls[i]);
        uint h[8], lo[8];
#pragma unroll
        for (int i = 0; i < 8; i++) {
            h[i] = (uint)hs[2 * i] | ((uint)hs[2 * i + 1] << 16);
            lo[i] = (uint)ls[2 * i] | ((uint)ls[2 * i + 1] << 16);
        }
        size_t o = (size_t)c * K + kb * 32 + g * 16;
        *(uint4*)&Wth[o] = make_uint4(h[0], h[1], h[2], h[3]);
        *(uint4*)&Wth[o + 8] = make_uint4(h[4], h[5], h[6], h[7]);
        *(uint4*)&Wtl[o] = make_uint4(lo[0], lo[1], lo[2], lo[3]);
        *(uint4*)&Wtl[o + 8] = make_uint4(lo[4], lo[5], lo[6], lo[7]);
    }
}

// ---------------- MFMA GEMM (fp32 input): 128x128 tile, fp16 A single plane ----------------
// LDS layout: kg-plane-major (plane = kg*2048 + idx*16) -> conflict-free ds_read_b128
// (16-lane fragment groups have uniform kg, consecutive idx => 16B-stride sweep).
template <int K>
__global__ __launch_bounds__(256) void mfma_gemm_f32(const float* __restrict__ X,
                                                     const ushort* __restrict__ Wth,
                                                     const ushort* __restrict__ Wtl,
                                                     const float* __restrict__ dinv,
                                                     uint* __restrict__ Y, int M) {
    __shared__ char smem[24 * 1024];
    char* aP = smem;              // 8 KB: 4 kg-planes x 128 rows x 16B (fp16)
    char* bH = smem + 8192;       // 8 KB
    char* bL = smem + 16384;      // 8 KB
    int tid = threadIdx.x;
    int w = tid >> 6, l = tid & 63;
    int rowBase = blockIdx.x * 128;

    f32x4 acc[2][8];
#pragma unroll
    for (int mf = 0; mf < 2; mf++)
#pragma unroll
        for (int n = 0; n < 8; n++) acc[mf][n] = (f32x4){0.f, 0.f, 0.f, 0.f};

    // A staging: thread t -> row t>>1, k-half t&1 (16 fp32)
    int sRow = tid >> 1, sKp = tid & 1;
    int gRow = rowBase + sRow;
    bool rowOK = gRow < M;
    size_t aBase = (size_t)(rowOK ? gRow : 0) * K + sKp * 16;

    float4 a0, a1, a2, a3;
    a0 = a1 = a2 = a3 = make_float4(0.f, 0.f, 0.f, 0.f);
    if (rowOK) {
        a0 = *(const float4*)&X[aBase];
        a1 = *(const float4*)&X[aBase + 4];
        a2 = *(const float4*)&X[aBase + 8];
        a3 = *(const float4*)&X[aBase + 12];
    }

    int fc = l & 15, fkg = l >> 4;
    int aoff0 = fkg * 2048 + ((2 * w + 0) * 16 + fc) * 16;
    int aoff1 = fkg * 2048 + ((2 * w + 1) * 16 + fc) * 16;

    for (int kt = 0; kt < K; kt += 32) {
        // ---- B async global->LDS (kg-plane chunk order: c -> kg=c>>7, col=c&127) ----
#pragma unroll
        for (int i = 0; i < 2; i++) {
            int cb = (i * 4 + w) * 64;   // wave-uniform
            int c = cb + l;
            int kg = c >> 7, colb = c & 127;
            size_t go = (size_t)colb * K + kt + kg * 8;
            gload16(&Wth[go], bH + cb * 16);
            gload16(&Wtl[go], bL + cb * 16);
        }
        // ---- cvt A regs -> fp16 plane ----
        {
            float v[16] = {a0.x, a0.y, a0.z, a0.w, a1.x, a1.y, a1.z, a1.w,
                           a2.x, a2.y, a2.z, a2.w, a3.x, a3.y, a3.z, a3.w};
            uint hh[8];
#pragma unroll
            for (int i = 0; i < 8; i++) hh[i] = f2h_pair(v[2 * i], v[2 * i + 1]);
            // chunks kg = 2*sKp, 2*sKp+1 at row sRow
            *(uint4*)(aP + (2 * sKp) * 2048 + sRow * 16) = make_uint4(hh[0], hh[1], hh[2], hh[3]);
            *(uint4*)(aP + (2 * sKp + 1) * 2048 + sRow * 16) = make_uint4(hh[4], hh[5], hh[6], hh[7]);
        }
        __syncthreads();

        // ---- prefetch next A tile (HBM latency hides under MFMA) ----
        if (kt + 32 < K && rowOK) {
            size_t nb = aBase + kt + 32;
            a0 = *(const float4*)&X[nb];
            a1 = *(const float4*)&X[nb + 4];
            a2 = *(const float4*)&X[nb + 8];
            a3 = *(const float4*)&X[nb + 12];
        }

        half8 av0 = *(const half8*)(aP + aoff0);
        half8 av1 = *(const half8*)(aP + aoff1);
#pragma unroll
        for (int n = 0; n < 8; n++) {
            int boff = fkg * 2048 + (16 * n + fc) * 16;
            half8 bh = *(const half8*)(bH + boff);
            half8 bl = *(const half8*)(bL + boff);
            acc[0][n] = __builtin_amdgcn_mfma_f32_16x16x32_f16(av0, bh, acc[0][n], 0, 0, 0);
            acc[0][n] = __builtin_amdgcn_mfma_f32_16x16x32_f16(av0, bl, acc[0][n], 0, 0, 0);
            acc[1][n] = __builtin_amdgcn_mfma_f32_16x16x32_f16(av1, bh, acc[1][n], 0, 0, 0);
            acc[1][n] = __builtin_amdgcn_mfma_f32_16x16x32_f16(av1, bl, acc[1][n], 0, 0, 0);
        }
        __syncthreads();
    }

    // ---- epilogue: scale by dinv, pack fp16 pairs ----
#pragma unroll
    for (int mf = 0; mf < 2; mf++) {
        float dscale[4];
#pragma unroll
        for (int r = 0; r < 4; r++) {
            int row = rowBase + (2 * w + mf) * 16 + fkg * 4 + r;
            dscale[r] = (row < M) ? dinv[row] : 0.f;
        }
#pragma unroll
        for (int n = 0; n < 8; n++) {
#pragma unroll
            for (int r = 0; r < 4; r++) {
                float val = acc[mf][n][r] * dscale[r];
                float p = __shfl_xor(val, 1, 64);
                int row = rowBase + (2 * w + mf) * 16 + fkg * 4 + r;
                if (!(l & 1) && row < M)
                    Y[(size_t)row * 64 + 8 * n + (fc >> 1)] = f2h_pair(val, p);
            }
        }
    }
}

// ---------------- MFMA GEMM (fp16 input, K=128): all staging via global_load_lds ----------------
__global__ __launch_bounds__(256) void mfma_gemm_f16(const ushort* __restrict__ Xh,
                                                     const ushort* __restrict__ Wth,
                                                     const ushort* __restrict__ Wtl,
                                                     const float* __restrict__ dinv,
                                                     uint* __restrict__ Y, int M) {
    __shared__ char smem[24 * 1024];
    char* aP = smem;
    char* bH = smem + 8192;
    char* bL = smem + 16384;
    int tid = threadIdx.x;
    int w = tid >> 6, l = tid & 63;
    int rowBase = blockIdx.x * 128;

    f32x4 acc[2][8];
#pragma unroll
    for (int mf = 0; mf < 2; mf++)
#pragma unroll
        for (int n = 0; n < 8; n++) acc[mf][n] = (f32x4){0.f, 0.f, 0.f, 0.f};

    int fc = l & 15, fkg = l >> 4;
    int aoff0 = fkg * 2048 + ((2 * w + 0) * 16 + fc) * 16;
    int aoff1 = fkg * 2048 + ((2 * w + 1) * 16 + fc) * 16;

    for (int kt = 0; kt < 128; kt += 32) {
#pragma unroll
        for (int i = 0; i < 2; i++) {
            int cb = (i * 4 + w) * 64;   // wave-uniform
            int c = cb + l;
            int kg = c >> 7, idx = c & 127;
            // A rows may run past M; reads stay inside d_ws (bufF region oversized), masked at epilogue
            gload16(&Xh[(size_t)(rowBase + idx) * 128 + kt + kg * 8], aP + cb * 16);
            gload16(&Wth[(size_t)idx * 128 + kt + kg * 8], bH + cb * 16);
            gload16(&Wtl[(size_t)idx * 128 + kt + kg * 8], bL + cb * 16);
        }
        __syncthreads();
        half8 av0 = *(const half8*)(aP + aoff0);
        half8 av1 = *(const half8*)(aP + aoff1);
#pragma unroll
        for (int n = 0; n < 8; n++) {
            int boff = fkg * 2048 + (16 * n + fc) * 16;
            half8 bh = *(const half8*)(bH + boff);
            half8 bl = *(const half8*)(bL + boff);
            acc[0][n] = __builtin_amdgcn_mfma_f32_16x16x32_f16(av0, bh, acc[0][n], 0, 0, 0);
            acc[0][n] = __builtin_amdgcn_mfma_f32_16x16x32_f16(av0, bl, acc[0][n], 0, 0, 0);
            acc[1][n] = __builtin_amdgcn_mfma_f32_16x16x32_f16(av1, bh, acc[1][n], 0, 0, 0);
            acc[1][n] = __builtin_amdgcn_mfma_f32_16x16x32_f16(av1, bl, acc[1][n], 0, 0, 0);
        }
        __syncthreads();
    }

#pragma unroll
    for (int mf = 0; mf < 2; mf++) {
        float dscale[4];
#pragma unroll
        for (int r = 0; r < 4; r++) {
            int row = rowBase + (2 * w + mf) * 16 + fkg * 4 + r;
            dscale[r] = (row < M) ? dinv[row] : 0.f;
        }
#pragma unroll
        for (int n = 0; n < 8; n++) {
#pragma unroll
            for (int r = 0; r < 4; r++) {
                float val = acc[mf][n][r] * dscale[r];
                float p = __shfl_xor(val, 1, 64);
                int row = rowBase + (2 * w + mf) * 16 + fkg * 4 + r;
                if (!(l & 1) && row < M)
                    Y[(size_t)row * 64 + 8 * n + (fc >> 1)] = f2h_pair(val, p);
            }
        }
    }
}

// ---------------- small GEMM, N=5, K=128, fp16 input: thread per row ----------------
__global__ __launch_bounds__(256) void gemm_n5h(const uint4* __restrict__ Xh,
                                                const float* __restrict__ W,
                                                float* __restrict__ Y, int M) {
    __shared__ float wl[640];
    int t = threadIdx.x;
    for (int i = t; i < 640; i += 256) wl[i] = W[i];
    __syncthreads();
    int row = blockIdx.x * 256 + t;
    if (row >= M) return;
    float acc0 = 0.f, acc1 = 0.f, acc2 = 0.f, acc3 = 0.f, acc4 = 0.f;
#pragma unroll
    for (int kq = 0; kq < 16; kq++) {
        uint4 v = Xh[(size_t)row * 16 + kq];
        uint uu[4] = {v.x, v.y, v.z, v.w};
#pragma unroll
        for (int e = 0; e < 4; e++) {
            float x0 = h2f_lo(uu[e]);
            float x1 = h2f_hi(uu[e]);
            int k = kq * 8 + e * 2;
            acc0 = fmaf(x0, wl[k * 5 + 0], acc0); acc0 = fmaf(x1, wl[k * 5 + 5], acc0);
            acc1 = fmaf(x0, wl[k * 5 + 1], acc1); acc1 = fmaf(x1, wl[k * 5 + 6], acc1);
            acc2 = fmaf(x0, wl[k * 5 + 2], acc2); acc2 = fmaf(x1, wl[k * 5 + 7], acc2);
            acc3 = fmaf(x0, wl[k * 5 + 3], acc3); acc3 = fmaf(x1, wl[k * 5 + 8], acc3);
            acc4 = fmaf(x0, wl[k * 5 + 4], acc4); acc4 = fmaf(x1, wl[k * 5 + 9], acc4);
        }
    }
    Y[row * 5 + 0] = acc0;
    Y[row * 5 + 1] = acc1;
    Y[row * 5 + 2] = acc2;
    Y[row * 5 + 3] = acc3;
    Y[row * 5 + 4] = acc4;
}

// ---------------- pack h5: fp32[5] * dinv[row] -> 8 fp16 (16B, padded) ----------------
__global__ void pack5(const float* __restrict__ Y, const float* __restrict__ dinv,
                      uint4* __restrict__ hc, int N) {
    int node = blockIdx.x * 256 + threadIdx.x;
    if (node >= N) return;
    float di = dinv[node];
    float v0 = Y[node * 5 + 0] * di;
    float v1 = Y[node * 5 + 1] * di;
    float v2 = Y[node * 5 + 2] * di;
    float v3 = Y[node * 5 + 3] * di;
    float v4 = Y[node * 5 + 4] * di;
    hc[node] = make_uint4(f2h_pair(v0, v1), f2h_pair(v2, v3), f2h_pair(v4, 0.f), 0u);
}

#define ACC8H(v)                              \
    a0 += h2f_lo(v.x); a1 += h2f_hi(v.x);     \
    a2 += h2f_lo(v.y); a3 += h2f_hi(v.y);     \
    a4 += h2f_lo(v.z); a5 += h2f_hi(v.z);     \
    a6 += h2f_lo(v.w); a7 += h2f_hi(v.w);

// ---------------- CSR aggregation, dim 128 (fp16): wave/node, out = fp16 rows ----------------
__global__ __launch_bounds__(256) void agg128_v3(const uint4* __restrict__ hb4,
                                                 const int* __restrict__ rowptr,
                                                 const int* __restrict__ col,
                                                 const float* __restrict__ dinv,
                                                 const float* __restrict__ bias,
                                                 uint4* __restrict__ out, int N, int do_relu) {
    int wave = threadIdx.x >> 6;
    int lane = threadIdx.x & 63;
    int node = blockIdx.x * 4 + wave;
    if (node >= N) return;
    int g = lane >> 4;    // edge slot 0..3
    int q = lane & 15;    // dim-octet: dims [q*8, q*8+8)
    int beg = rowptr[node], end = rowptr[node + 1];
    float a0 = 0.f, a1 = 0.f, a2 = 0.f, a3 = 0.f, a4 = 0.f, a5 = 0.f, a6 = 0.f, a7 = 0.f;

    int j = beg;
    for (; j + 16 <= end; j += 16) {
        int s0 = col[j + g];
        int s1 = col[j + 4 + g];
        int s2 = col[j + 8 + g];
        int s3 = col[j + 12 + g];
        uint4 v0 = hb4[(size_t)s0 * 16 + q];
        uint4 v1 = hb4[(size_t)s1 * 16 + q];
        uint4 v2 = hb4[(size_t)s2 * 16 + q];
        uint4 v3 = hb4[(size_t)s3 * 16 + q];
        ACC8H(v0); ACC8H(v1); ACC8H(v2); ACC8H(v3);
    }
    if (j + 8 <= end) {
        int s0 = col[j + g];
        int s1 = col[j + 4 + g];
        uint4 v0 = hb4[(size_t)s0 * 16 + q];
        uint4 v1 = hb4[(size_t)s1 * 16 + q];
        ACC8H(v0); ACC8H(v1);
        j += 8;
    }
    if (j < end) {
        int jj0 = j + g, jj1 = j + 4 + g;
        bool p0 = jj0 < end, p1 = jj1 < end;
        int s0 = p0 ? col[jj0] : node;
        int s1 = p1 ? col[jj1] : node;
        uint4 v0 = hb4[(size_t)s0 * 16 + q];
        uint4 v1 = hb4[(size_t)s1 * 16 + q];
        if (!p0) v0 = make_uint4(0u, 0u, 0u, 0u);
        if (!p1) v1 = make_uint4(0u, 0u, 0u, 0u);
        ACC8H(v0); ACC8H(v1);
    }
#pragma unroll
    for (int off = 16; off <= 32; off <<= 1) {
        a0 += __shfl_xor(a0, off, 64);
        a1 += __shfl_xor(a1, off, 64);
        a2 += __shfl_xor(a2, off, 64);
        a3 += __shfl_xor(a3, off, 64);
        a4 += __shfl_xor(a4, off, 64);
        a5 += __shfl_xor(a5, off, 64);
        a6 += __shfl_xor(a6, off, 64);
        a7 += __shfl_xor(a7, off, 64);
    }
    if (g == 0) {
        uint4 vs = hb4[(size_t)node * 16 + q];  // self term (pre-scaled)
        ACC8H(vs);
        float di = dinv[node];
        const float4* bias4 = (const float4*)bias;
        float4 bb0 = bias4[q * 2], bb1 = bias4[q * 2 + 1];
        float o0 = a0 * di + bb0.x, o1 = a1 * di + bb0.y;
        float o2 = a2 * di + bb0.z, o3 = a3 * di + bb0.w;
        float o4 = a4 * di + bb1.x, o5 = a5 * di + bb1.y;
        float o6 = a6 * di + bb1.z, o7 = a7 * di + bb1.w;
        if (do_relu) {
            o0 = fmaxf(o0, 0.f); o1 = fmaxf(o1, 0.f);
            o2 = fmaxf(o2, 0.f); o3 = fmaxf(o3, 0.f);
            o4 = fmaxf(o4, 0.f); o5 = fmaxf(o5, 0.f);
            o6 = fmaxf(o6, 0.f); o7 = fmaxf(o7, 0.f);
        }
        out[(size_t)node * 16 + q] =
            make_uint4(f2h_pair(o0, o1), f2h_pair(o2, o3), f2h_pair(o4, o5), f2h_pair(o6, o7));
    }
}

// ---------------- CSR aggregation, dim 5 (fp16 packed rows): thread per node ----------------
__global__ void agg5_v2(const uint4* __restrict__ hc, const int* __restrict__ rowptr,
                        const int* __restrict__ col, const float* __restrict__ dinv,
                        const float* __restrict__ b3, float* __restrict__ out, int N) {
    int node = blockIdx.x * 256 + threadIdx.x;
    if (node >= N) return;
    float a0 = 0.f, a1 = 0.f, a2 = 0.f, a3 = 0.f, a4 = 0.f;
    int beg = rowptr[node], end = rowptr[node + 1];
#pragma unroll 2
    for (int j = beg; j < end; ++j) {
        uint4 v = hc[col[j]];
        a0 += h2f_lo(v.x); a1 += h2f_hi(v.x);
        a2 += h2f_lo(v.y); a3 += h2f_hi(v.y);
        a4 += h2f_lo(v.z);
    }
    uint4 vs = hc[node];
    a0 += h2f_lo(vs.x); a1 += h2f_hi(vs.x);
    a2 += h2f_lo(vs.y); a3 += h2f_hi(vs.y);
    a4 += h2f_lo(vs.z);
    float di = dinv[node];
    out[node * 5 + 0] = a0 * di + b3[0];
    out[node * 5 + 1] = a1 * di + b3[1];
    out[node * 5 + 2] = a2 * di + b3[2];
    out[node * 5 + 3] = a3 * di + b3[3];
    out[node * 5 + 4] = a4 * di + b3[4];
}

static inline size_t align512(size_t x) { return (x + 511) & ~(size_t)511; }

extern "C" void kernel_launch(void* const* d_in, const int* in_sizes, int n_in,
                              void* d_out, int out_size, void* d_ws, size_t ws_size,
                              hipStream_t stream) {
    const float* x  = (const float*)d_in[0];
    const int* ei   = (const int*)d_in[1];
    const float* W1 = (const float*)d_in[2];
    const float* b1 = (const float*)d_in[3];
    const float* W2 = (const float*)d_in[4];
    const float* b2 = (const float*)d_in[5];
    const float* W3 = (const float*)d_in[6];
    const float* b3 = (const float*)d_in[7];
    const int* src = ei;
    const int* dst = ei + NE;

    char* ws = (char*)d_ws;
    size_t off = 0;
    int* cnt = (int*)(ws + off);        off += align512((size_t)NN * 4);
    int* rowptr = (int*)(ws + off);     off += align512((size_t)(NN + 1) * 4);
    float* dinv = (float*)(ws + off);   off += align512((size_t)NN * 4);
    int* bsum = (int*)(ws + off);       off += align512((size_t)128 * 4);
    int* ghist = (int*)(ws + off);      off += align512((size_t)GH * 4);
    ushort* wt1h = (ushort*)(ws + off); off += align512((size_t)128 * 384 * 2);
    ushort* wt1l = (ushort*)(ws + off); off += align512((size_t)128 * 384 * 2);
    ushort* wt2h = (ushort*)(ws + off); off += align512((size_t)128 * 128 * 2);
    ushort* wt2l = (ushort*)(ws + off); off += align512((size_t)128 * 128 * 2);
    int* col = (int*)(ws + off);        off += align512((size_t)NE * 4);
    uint* hb = (uint*)(ws + off);       off += align512((size_t)NN * 64 * 4);   // fp16 dinv*h (packed)
    char* bufF = (char*)(ws + off);     off += align512((size_t)NN * 128 * 4);  // fp16 agg out (region oversized: OOB-tile reads stay in ws)
    float* bufC = (float*)(ws + off);   off += align512((size_t)NN * 5 * 4);
    uint4* hc = (uint4*)(ws + off);     off += align512((size_t)NN * 16);       // packed fp16 dinv*h5
    uint* binned = (uint*)bufF;  // alias: binned dead before bufF's first write
    (void)ws_size;

    // ---- W transpose + fp16 hi/lo split ----
    wsplit<384><<<12, 256, 0, stream>>>(W1, wt1h, wt1l);
    wsplit<128><<<4, 256, 0, stream>>>(W2, wt2h, wt2l);

    // ---- build CSR (by dst) + dinv, bucket-sorted for write locality ----
    hist_bkt<<<BIN_BLOCKS, 256, 0, stream>>>(dst, ghist);
    {
        int nb = (GH + SCAN_CHUNK - 1) / SCAN_CHUNK;  // 98
        scan_p1<<<nb, 256, 0, stream>>>(ghist, bsum, GH);
        scan_p2<<<1, 128, 0, stream>>>(bsum, nb);
        scan_p3_plain<<<nb, 256, 0, stream>>>(ghist, bsum, GH);
    }
    bin_edges<<<BIN_BLOCKS, 256, 0, stream>>>(src, dst, ghist, binned);
    bucket_count<<<NBKT, 256, 0, stream>>>(binned, ghist, cnt);
    {
        int nb = (NN + SCAN_CHUNK - 1) / SCAN_CHUNK;  // 98
        scan_p1<<<nb, 256, 0, stream>>>(cnt, bsum, NN);
        scan_p2<<<1, 128, 0, stream>>>(bsum, nb);
        scan_p3_deg<<<nb, 256, 0, stream>>>(cnt, bsum, rowptr, dinv, NN);
    }
    csr_fill<<<NBKT, 256, 0, stream>>>(binned, ghist, rowptr, col);

    int gemm_blocks = (NN + 127) / 128;  // 782
    // ---- layer 1 ----
    mfma_gemm_f32<384><<<gemm_blocks, 256, 0, stream>>>(x, wt1h, wt1l, dinv, hb, NN);
    agg128_v3<<<(NN + 3) / 4, 256, 0, stream>>>((const uint4*)hb, rowptr, col, dinv, b1,
                                                (uint4*)bufF, NN, 1);
    // ---- layer 2 ----
    mfma_gemm_f16<<<gemm_blocks, 256, 0, stream>>>((const ushort*)bufF, wt2h, wt2l, dinv, hb, NN);
    agg128_v3<<<(NN + 3) / 4, 256, 0, stream>>>((const uint4*)hb, rowptr, col, dinv, b2,
                                                (uint4*)bufF, NN, 1);
    // ---- layer 3 ----
    gemm_n5h<<<(NN + 255) / 256, 256, 0, stream>>>((const uint4*)bufF, W3, bufC, NN);
    pack5<<<(NN + 255) / 256, 256, 0, stream>>>(bufC, dinv, hc, NN);
    agg5_v2<<<(NN + 255) / 256, 256, 0, stream>>>(hc, rowptr, col, dinv, b3, (float*)d_out, NN);
}